// Round 8
// baseline (268.530 us; speedup 1.0000x reference)
//
#include <hip/hip_runtime.h>
#include <hip/hip_bf16.h>

typedef float f32x4 __attribute__((ext_vector_type(4)));
typedef float f32x2 __attribute__((ext_vector_type(2)));
typedef short bf16x8 __attribute__((ext_vector_type(8)));
typedef unsigned uint4v __attribute__((ext_vector_type(4)));

#define B_ 32
#define L_ 1024
#define D_ 64
#define J_ 2047   // 2L-1
#define BL_ (B_ * L_)

// packed f32x2 -> bf16x2 (RNE), single instruction
__device__ __forceinline__ unsigned cvt_pk(float lo, float hi) {
    unsigned r;
    asm("v_cvt_pk_bf16_f32 %0, %1, %2" : "=v"(r) : "v"(lo), "v"(hi));
    return r;
}

__device__ __forceinline__ bf16x8 pack8n(const float* p) {
    float4 a = *(const float4*)p;
    float4 c = *(const float4*)(p + 4);
    union { bf16x8 s; uint4v u; } r;
    r.u[0] = cvt_pk(a.x, a.y);
    r.u[1] = cvt_pk(a.z, a.w);
    r.u[2] = cvt_pk(c.x, c.y);
    r.u[3] = cvt_pk(c.z, c.w);
    return r.s;
}

// f32 -> fp16 (RNE) and back, single v_cvt instructions
__device__ __forceinline__ unsigned short f2h(float f) {
    unsigned r;
    asm("v_cvt_f16_f32 %0, %1" : "=v"(r) : "v"(f));
    return (unsigned short)r;
}
__device__ __forceinline__ float h2fl(unsigned u) {   // low half -> f32
    float r;
    asm("v_cvt_f32_f16 %0, %1" : "=v"(r) : "v"(u));
    return r;
}
__device__ __forceinline__ float h2fh(unsigned u) {   // high half -> f32
    float r;
    asm("v_cvt_f32_f16 %0, %1" : "=v"(r) : "v"(u >> 16));
    return r;
}

// Detect attn_mask storage: 0 = 1-byte bool, 1 = int32 0/1, 2 = float32 0.0/1.0
__global__ void detect_mask_kernel(const unsigned int* __restrict__ mw, int* __restrict__ flag) {
    if (threadIdx.x == 0) {
        int all01 = 1, allf = 1;
        for (int i = 0; i < 64; ++i) {
            unsigned w = mw[i];
            if (w > 1u) all01 = 0;
            if (w != 0u && w != 0x3F800000u) allf = 0;
        }
        *flag = all01 ? 1 : (allf ? 2 : 0);
    }
}

// Elementwise f32 -> bf16 (8 elems/thread, coalesced)
__global__ __launch_bounds__(256) void cvt_bf16_kernel(
    const float* __restrict__ src, unsigned short* __restrict__ dst, int n8)
{
    int i = blockIdx.x * 256 + threadIdx.x;
    if (i < n8) {
        float4 a = ((const float4*)src)[2 * i];
        float4 c = ((const float4*)src)[2 * i + 1];
        uint4v u;
        u[0] = cvt_pk(a.x, a.y); u[1] = cvt_pk(a.z, a.w);
        u[2] = cvt_pk(c.x, c.y); u[3] = cvt_pk(c.z, c.w);
        ((uint4v*)dst)[i] = u;
    }
}

// Transpose V[b][1024][64] f32 -> vt[b][64][1024] bf16
__global__ __launch_bounds__(256) void vtrans(
    const float* __restrict__ V, unsigned short* __restrict__ vt)
{
    __shared__ float tile[64 * 68];
    const int b = blockIdx.x >> 4, mt = blockIdx.x & 15;
    const int m0 = mt * 64;
    const int tid = threadIdx.x;
    {
        const int ml = tid >> 2, dq = tid & 3;
        const float* src = V + (size_t)(b * L_ + m0 + ml) * D_ + dq * 16;
        #pragma unroll
        for (int i = 0; i < 4; ++i)
            *(float4*)&tile[ml * 68 + dq * 16 + i * 4] = *(const float4*)(src + i * 4);
    }
    __syncthreads();
    {
        const int d = tid >> 2, mq = tid & 3;
        unsigned u[8];
        #pragma unroll
        for (int j = 0; j < 8; ++j)
            u[j] = cvt_pk(tile[(mq * 16 + 2 * j) * 68 + d],
                          tile[(mq * 16 + 2 * j + 1) * 68 + d]);
        unsigned short* dst = vt + ((size_t)b * D_ + d) * L_ + m0 + mq * 16;
        *(uint4v*)dst       = *(uint4v*)&u[0];
        *(uint4v*)(dst + 8) = *(uint4v*)&u[4];
    }
}

// slog (fp16) swizzled index: row rl (0..15), col (0..1023)
__device__ __forceinline__ int sidx(int rl, int col) {
    return rl * 1024 + ((((col >> 3) ^ (rl & 15)) << 3) | (col & 7));
}
// opart (f32 overlay) swizzled index: row rr (0..127), col (0..63)
__device__ __forceinline__ int oidx(int rr, int col) {
    return rr * 64 + ((((col >> 2) ^ (rr & 15)) << 2) | (col & 3));
}

// Fused: logits -> fp16 LDS, online stats, softmax probs written once, PV MFMA.
// Block = 16 rows x 1024 cols, 8 waves (8 col-splits), 512 thr, ~33 KB LDS.
// PREP: 2 = K/P/V^T pre-converted bf16 in ws; 1 = only V^T; 0 = none.
template<int PREP>
__global__ __launch_bounds__(512, PREP == 2 ? 8 : 6) void fused_attn(
    const float* __restrict__ Q, const float* __restrict__ K,
    const float* __restrict__ QP, const float* __restrict__ P,
    const void* __restrict__ mask, const int* __restrict__ flagp,
    const unsigned short* __restrict__ vtg, const float* __restrict__ V,
    const unsigned short* __restrict__ kbf, const unsigned short* __restrict__ pbf,
    float* __restrict__ attn, float* __restrict__ out)
{
    __shared__ __align__(16) unsigned short slogb[16 * 1024];  // 32 KB fp16 logits
    __shared__ float pm[8][16][2];

    const int flag = *flagp;
    const int bid = blockIdx.x;
    const int xcd = bid & 7, ii = bid >> 3;          // 2048 = 8 * 256
    const int b   = xcd * 4 + (ii >> 6);             // pin batch group to XCD L2
    const int rb  = ii & 63;
    const int t0  = rb * 16;
    const int tid = threadIdx.x;
    const int lane = tid & 63;
    const int wc   = tid >> 6;                       // 0..7 col-split
    const int lr = lane & 15, lg = lane >> 4;

    bf16x8 aq[2], aqp[2];
    {
        const float* qrow  = Q  + (size_t)((b * L_ + t0 + lr) * D_ + lg * 8);
        const float* qprow = QP + (size_t)((b * L_ + t0 + lr) * D_ + lg * 8);
        aq[0]  = pack8n(qrow);   aq[1]  = pack8n(qrow + 32);
        aqp[0] = pack8n(qprow);  aqp[1] = pack8n(qprow + 32);
    }
    const unsigned char* m8  = (const unsigned char*)mask;
    const int*   m32p = (const int*)mask;
    const float* mfp  = (const float*)mask;

    float m_run[4] = {-1e30f, -1e30f, -1e30f, -1e30f};
    float l_run[4] = {0.f, 0.f, 0.f, 0.f};

    // ---------------- pass 1: logits -> LDS (fp16), online stats ----------------
    #pragma unroll 1
    for (int c = 0; c < 2; ++c) {
        const int m0 = wc * 128 + c * 64;
        f32x4 qk[4];
        #pragma unroll
        for (int ct = 0; ct < 4; ++ct) {
            bf16x8 b0, b1;
            if (PREP == 2) {
                const unsigned short* kr = kbf + (size_t)(b * L_ + m0 + ct * 16 + lr) * D_ + lg * 8;
                b0 = *(const bf16x8*)kr; b1 = *(const bf16x8*)(kr + 32);
            } else {
                const float* kr = K + (size_t)((b * L_ + m0 + ct * 16 + lr) * D_ + lg * 8);
                b0 = pack8n(kr); b1 = pack8n(kr + 32);
            }
            f32x4 acc = {0.f, 0.f, 0.f, 0.f};
            acc = __builtin_amdgcn_mfma_f32_16x16x32_bf16(aq[0], b0, acc, 0, 0, 0);
            acc = __builtin_amdgcn_mfma_f32_16x16x32_bf16(aq[1], b1, acc, 0, 0, 0);
            qk[ct] = acc;
        }
        const int jb = 1023 + m0 - t0 - 15;
        f32x4 pa[5];
        #pragma unroll
        for (int ss = 0; ss < 5; ++ss) {
            int j = jb + ss * 16 + lr;
            j = j < 0 ? 0 : (j > J_ - 1 ? J_ - 1 : j);
            bf16x8 b0, b1;
            if (PREP == 2) {
                const unsigned short* pr = pbf + (size_t)(b * J_ + j) * D_ + lg * 8;
                b0 = *(const bf16x8*)pr; b1 = *(const bf16x8*)(pr + 32);
            } else {
                const float* pr = P + (size_t)((b * J_ + j) * D_ + lg * 8);
                b0 = pack8n(pr); b1 = pack8n(pr + 32);
            }
            f32x4 acc = {0.f, 0.f, 0.f, 0.f};
            acc = __builtin_amdgcn_mfma_f32_16x16x32_bf16(aqp[0], b0, acc, 0, 0, 0);
            acc = __builtin_amdgcn_mfma_f32_16x16x32_bf16(aqp[1], b1, acc, 0, 0, 0);
            pa[ss] = acc;
        }
        #pragma unroll
        for (int r = 0; r < 4; ++r) {
            const int ti = lg * 4 + r;               // row within 16-tile
            const int t  = t0 + ti;
            // coalesced mask: one dword (4 cols) per lane, shfl-redistribute
            const size_t rowoff = (size_t)(b * L_ + t) * L_ + m0;
            unsigned mw;
            if (flag == 0) {
                mw = __builtin_nontemporal_load((const unsigned*)(m8 + rowoff) + lr);
            } else if (flag == 1) {
                int4 mi = ((const int4*)(m32p + rowoff))[lr];
                mw = (mi.x ? 1u : 0u) | (mi.y ? 0x100u : 0u)
                   | (mi.z ? 0x10000u : 0u) | (mi.w ? 0x1000000u : 0u);
            } else {
                float4 mv = ((const float4*)(mfp + rowoff))[lr];
                mw = (mv.x != 0.f ? 1u : 0u) | (mv.y != 0.f ? 0x100u : 0u)
                   | (mv.z != 0.f ? 0x10000u : 0u) | (mv.w != 0.f ? 0x1000000u : 0u);
            }
            const int jj = 15 + lr - ti;             // 0..30
            const int srcl = (lane & 48) | (jj & 15);
            float sv[4];
            #pragma unroll
            for (int ct = 0; ct < 4; ++ct) {
                float v0 = __shfl(pa[ct][r],     srcl);
                float v1 = __shfl(pa[ct + 1][r], srcl);
                float pos = (jj < 16) ? v0 : v1;
                float s = (qk[ct][r] + pos) * 0.125f;
                unsigned mb = ((unsigned)__shfl((int)mw, (lane & 48) | (ct * 4 + (lr >> 2)))
                               >> ((lr & 3) * 8)) & 0xFFu;
                if (mb) s = -__builtin_inff();
                sv[ct] = s;
                slogb[sidx(ti, m0 + ct * 16 + lr)] = f2h(s);
            }
            float cm = fmaxf(fmaxf(sv[0], sv[1]), fmaxf(sv[2], sv[3]));
            float mn = fmaxf(m_run[r], cm);
            float e = __expf(sv[0] - mn) + __expf(sv[1] - mn)
                    + __expf(sv[2] - mn) + __expf(sv[3] - mn);
            l_run[r] = l_run[r] * __expf(m_run[r] - mn) + e;
            m_run[r] = mn;
        }
    }
    // cross-lane merge within lr group, publish partial stats
    #pragma unroll
    for (int r = 0; r < 4; ++r) {
        float m = m_run[r], l = l_run[r];
        #pragma unroll
        for (int d = 1; d < 16; d <<= 1) {
            float mo = __shfl_xor(m, d);
            float lo = __shfl_xor(l, d);
            float mn = fmaxf(m, mo);
            l = l * __expf(m - mn) + lo * __expf(mo - mn);
            m = mn;
        }
        if (lr == 0) {
            pm[wc][lg * 4 + r][0] = m;
            pm[wc][lg * 4 + r][1] = l;
        }
    }
    __syncthreads();

    // ---------------- pass 2: probs (write once) + PV MFMA ----------------
    const int rl = lr;
    const int t  = t0 + rl;
    float M = -1e30f;
    #pragma unroll
    for (int s2 = 0; s2 < 8; ++s2) M = fmaxf(M, pm[s2][rl][0]);
    float Ls = 0.f;
    #pragma unroll
    for (int s2 = 0; s2 < 8; ++s2) Ls += pm[s2][rl][1] * __expf(pm[s2][rl][0] - M);
    float inv = 1.0f / Ls;
    float* arow = attn + (size_t)(b * L_ + t) * L_;

    f32x4 acc[4] = {{0,0,0,0},{0,0,0,0},{0,0,0,0},{0,0,0,0}};
    #pragma unroll
    for (int kc = 0; kc < 4; ++kc) {
        const int colb = wc * 128 + kc * 32 + lg * 8;
        uint4v u = *(const uint4v*)&slogb[sidx(rl, colb)];
        float p0 = __expf(h2fl(u[0]) - M) * inv, p1 = __expf(h2fh(u[0]) - M) * inv;
        float p2 = __expf(h2fl(u[1]) - M) * inv, p3 = __expf(h2fh(u[1]) - M) * inv;
        float p4 = __expf(h2fl(u[2]) - M) * inv, p5 = __expf(h2fh(u[2]) - M) * inv;
        float p6 = __expf(h2fl(u[3]) - M) * inv, p7 = __expf(h2fh(u[3]) - M) * inv;
        f32x4 y0 = {p0, p1, p2, p3};
        f32x4 y1 = {p4, p5, p6, p7};
        *(f32x4*)(arow + colb)     = y0;             // regular stores: L2 merges lines
        *(f32x4*)(arow + colb + 4) = y1;
        union { bf16x8 s; uint4v u; } ap;
        ap.u[0] = cvt_pk(p0, p1); ap.u[1] = cvt_pk(p2, p3);
        ap.u[2] = cvt_pk(p4, p5); ap.u[3] = cvt_pk(p6, p7);
        #pragma unroll
        for (int ct = 0; ct < 4; ++ct) {
            bf16x8 bv;
            if (PREP >= 1) {
                bv = *(const bf16x8*)&vtg[((size_t)b * D_ + ct * 16 + lr) * L_ + colb];
            } else {
                const float* vp = V + (size_t)(b * L_ + colb) * D_ + ct * 16 + lr;
                union { bf16x8 s; uint4v u; } bb;
                bb.u[0] = cvt_pk(vp[0],   vp[64]);
                bb.u[1] = cvt_pk(vp[128], vp[192]);
                bb.u[2] = cvt_pk(vp[256], vp[320]);
                bb.u[3] = cvt_pk(vp[384], vp[448]);
                bv = bb.s;
            }
            acc[ct] = __builtin_amdgcn_mfma_f32_16x16x32_bf16(ap.s, bv, acc[ct], 0, 0, 0);
        }
    }
    __syncthreads();                                 // all slog reads complete
    // partial O overlaid on slog: opart rows [wc*16, wc*16+16)
    float* opart = (float*)slogb;
    #pragma unroll
    for (int ct = 0; ct < 4; ++ct) {
        #pragma unroll
        for (int r = 0; r < 4; ++r)
            opart[oidx(wc * 16 + lg * 4 + r, ct * 16 + lr)] = acc[ct][r];
    }
    __syncthreads();
    {
        const int row = tid >> 5, dg = (tid & 31) * 2;
        f32x2 o = {0.f, 0.f};
        #pragma unroll
        for (int wq = 0; wq < 8; ++wq) {
            f32x2 z = *(f32x2*)&opart[oidx(wq * 16 + row, dg)];
            o[0] += z[0]; o[1] += z[1];
        }
        __builtin_nontemporal_store(o, (f32x2*)(out + (size_t)(b * L_ + t0 + row) * D_ + dg));
    }
}

extern "C" void kernel_launch(void* const* d_in, const int* in_sizes, int n_in,
                              void* d_out, int out_size, void* d_ws, size_t ws_size,
                              hipStream_t stream) {
    const float* q    = (const float*)d_in[0];
    const float* k    = (const float*)d_in[1];
    const float* v    = (const float*)d_in[2];
    const void*  mask = d_in[3];
    const float* P    = (const float*)d_in[4];
    const float* qp   = (const float*)d_in[5];

    float* out  = (float*)d_out;                  // [B, L, D]
    float* attn = out + B_ * L_ * D_;             // [B, L, L]

    int* flag = (int*)d_ws;
    unsigned short* vtg = (unsigned short*)((char*)d_ws + 64);
    unsigned short* kbf = vtg + (size_t)B_ * D_ * L_;
    unsigned short* pbf = kbf + (size_t)B_ * L_ * D_;
    const size_t need1 = 64 + (size_t)B_ * D_ * L_ * 2;
    const size_t need2 = need1 + (size_t)B_ * L_ * D_ * 2 + (size_t)B_ * J_ * D_ * 2;

    detect_mask_kernel<<<1, 64, 0, stream>>>((const unsigned int*)mask, flag);
    if (ws_size >= need2) {
        vtrans<<<B_ * 16, 256, 0, stream>>>(v, vtg);
        cvt_bf16_kernel<<<(B_ * L_ * D_ / 8 + 255) / 256, 256, 0, stream>>>(k, kbf, B_ * L_ * D_ / 8);
        cvt_bf16_kernel<<<(B_ * J_ * D_ / 8 + 255) / 256, 256, 0, stream>>>(P, pbf, B_ * J_ * D_ / 8);
        fused_attn<2><<<B_ * 64, 512, 0, stream>>>(q, k, qp, P, mask, flag, vtg, v, kbf, pbf, attn, out);
    } else if (ws_size >= need1) {
        vtrans<<<B_ * 16, 256, 0, stream>>>(v, vtg);
        fused_attn<1><<<B_ * 64, 512, 0, stream>>>(q, k, qp, P, mask, flag, vtg, v, kbf, pbf, attn, out);
    } else {
        fused_attn<0><<<B_ * 64, 512, 0, stream>>>(q, k, qp, P, mask, flag, vtg, v, kbf, pbf, attn, out);
    }
}

// Round 9
// 257.494 us; speedup vs baseline: 1.0429x; 1.0429x over previous
//
#include <hip/hip_runtime.h>
#include <hip/hip_bf16.h>

typedef float f32x4 __attribute__((ext_vector_type(4)));
typedef float f32x2 __attribute__((ext_vector_type(2)));
typedef short bf16x8 __attribute__((ext_vector_type(8)));
typedef unsigned uint4v __attribute__((ext_vector_type(4)));
typedef unsigned short u16x4 __attribute__((ext_vector_type(4)));

#define B_ 32
#define L_ 1024
#define D_ 64
#define J_ 2047   // 2L-1
#define BL_ (B_ * L_)

// packed f32x2 -> bf16x2 (RNE), single instruction
__device__ __forceinline__ unsigned cvt_pk(float lo, float hi) {
    unsigned r;
    asm("v_cvt_pk_bf16_f32 %0, %1, %2" : "=v"(r) : "v"(lo), "v"(hi));
    return r;
}

__device__ __forceinline__ bf16x8 pack8n(const float* p) {
    float4 a = *(const float4*)p;
    float4 c = *(const float4*)(p + 4);
    union { bf16x8 s; uint4v u; } r;
    r.u[0] = cvt_pk(a.x, a.y);
    r.u[1] = cvt_pk(a.z, a.w);
    r.u[2] = cvt_pk(c.x, c.y);
    r.u[3] = cvt_pk(c.z, c.w);
    return r.s;
}

// f32 -> fp16 (RNE) and back, single v_cvt instructions
__device__ __forceinline__ unsigned short f2h(float f) {
    unsigned r;
    asm("v_cvt_f16_f32 %0, %1" : "=v"(r) : "v"(f));
    return (unsigned short)r;
}
__device__ __forceinline__ float h2f(unsigned u) {    // low half -> f32
    float r;
    asm("v_cvt_f32_f16 %0, %1" : "=v"(r) : "v"(u));
    return r;
}
__device__ __forceinline__ float h2fh(unsigned u) {   // high half -> f32
    float r;
    asm("v_cvt_f32_f16 %0, %1" : "=v"(r) : "v"(u >> 16));
    return r;
}

// Detect attn_mask storage: 0 = 1-byte bool, 1 = int32 0/1, 2 = float32 0.0/1.0
__global__ void detect_mask_kernel(const unsigned int* __restrict__ mw, int* __restrict__ flag) {
    if (threadIdx.x == 0) {
        int all01 = 1, allf = 1;
        for (int i = 0; i < 64; ++i) {
            unsigned w = mw[i];
            if (w > 1u) all01 = 0;
            if (w != 0u && w != 0x3F800000u) allf = 0;
        }
        *flag = all01 ? 1 : (allf ? 2 : 0);
    }
}

// Elementwise f32 -> bf16 (8 elems/thread, coalesced)
__global__ __launch_bounds__(256) void cvt_bf16_kernel(
    const float* __restrict__ src, unsigned short* __restrict__ dst, int n8)
{
    int i = blockIdx.x * 256 + threadIdx.x;
    if (i < n8) {
        float4 a = ((const float4*)src)[2 * i];
        float4 c = ((const float4*)src)[2 * i + 1];
        uint4v u;
        u[0] = cvt_pk(a.x, a.y); u[1] = cvt_pk(a.z, a.w);
        u[2] = cvt_pk(c.x, c.y); u[3] = cvt_pk(c.z, c.w);
        ((uint4v*)dst)[i] = u;
    }
}

// Transpose V[b][1024][64] f32 -> vt[b][64][1024] bf16
__global__ __launch_bounds__(256) void vtrans(
    const float* __restrict__ V, unsigned short* __restrict__ vt)
{
    __shared__ float tile[64 * 68];
    const int b = blockIdx.x >> 4, mt = blockIdx.x & 15;
    const int m0 = mt * 64;
    const int tid = threadIdx.x;
    {
        const int ml = tid >> 2, dq = tid & 3;
        const float* src = V + (size_t)(b * L_ + m0 + ml) * D_ + dq * 16;
        #pragma unroll
        for (int i = 0; i < 4; ++i)
            *(float4*)&tile[ml * 68 + dq * 16 + i * 4] = *(const float4*)(src + i * 4);
    }
    __syncthreads();
    {
        const int d = tid >> 2, mq = tid & 3;
        unsigned u[8];
        #pragma unroll
        for (int j = 0; j < 8; ++j)
            u[j] = cvt_pk(tile[(mq * 16 + 2 * j) * 68 + d],
                          tile[(mq * 16 + 2 * j + 1) * 68 + d]);
        unsigned short* dst = vt + ((size_t)b * D_ + d) * L_ + m0 + mq * 16;
        *(uint4v*)dst       = *(uint4v*)&u[0];
        *(uint4v*)(dst + 8) = *(uint4v*)&u[4];
    }
}

// slog (fp16) swizzled index: row rl (0..15), col (0..1023)
__device__ __forceinline__ int sidx(int rl, int col) {
    return rl * 1024 + ((((col >> 3) ^ (rl & 15)) << 3) | (col & 7));
}
// opart (f32 overlay) swizzled index: row rr (0..127), col (0..63)
__device__ __forceinline__ int oidx(int rr, int col) {
    return rr * 64 + ((((col >> 2) ^ (rr & 15)) << 2) | (col & 3));
}

// Fused: logits -> fp16 LDS, online stats, PV MFMA, then row-major coalesced
// NT probs stores (full cache lines, no L2 pollution).
// Block = 16 rows x 1024 cols, 8 waves (8 col-splits), 512 thr, ~33 KB LDS.
// PREP: 2 = K/P/V^T pre-converted bf16 in ws; 1 = only V^T; 0 = none.
template<int PREP>
__global__ __launch_bounds__(512, PREP == 2 ? 8 : 6) void fused_attn(
    const float* __restrict__ Q, const float* __restrict__ K,
    const float* __restrict__ QP, const float* __restrict__ P,
    const void* __restrict__ mask, const int* __restrict__ flagp,
    const unsigned short* __restrict__ vtg, const float* __restrict__ V,
    const unsigned short* __restrict__ kbf, const unsigned short* __restrict__ pbf,
    float* __restrict__ attn, float* __restrict__ out)
{
    __shared__ __align__(16) unsigned short slogb[16 * 1024];  // 32 KB fp16 logits
    __shared__ float pm[8][16][2];
    __shared__ float Mrow[16], Irow[16];

    const int flag = *flagp;
    const int bid = blockIdx.x;
    const int xcd = bid & 7, ii = bid >> 3;          // 2048 = 8 * 256
    const int b   = xcd * 4 + (ii >> 6);             // pin batch group to XCD L2
    const int rb  = ii & 63;
    const int t0  = rb * 16;
    const int tid = threadIdx.x;
    const int lane = tid & 63;
    const int wc   = tid >> 6;                       // 0..7 col-split
    const int lr = lane & 15, lg = lane >> 4;

    bf16x8 aq[2], aqp[2];
    {
        const float* qrow  = Q  + (size_t)((b * L_ + t0 + lr) * D_ + lg * 8);
        const float* qprow = QP + (size_t)((b * L_ + t0 + lr) * D_ + lg * 8);
        aq[0]  = pack8n(qrow);   aq[1]  = pack8n(qrow + 32);
        aqp[0] = pack8n(qprow);  aqp[1] = pack8n(qprow + 32);
    }
    const unsigned char* m8  = (const unsigned char*)mask;
    const int*   m32p = (const int*)mask;
    const float* mfp  = (const float*)mask;

    float m_run[4] = {-1e30f, -1e30f, -1e30f, -1e30f};
    float l_run[4] = {0.f, 0.f, 0.f, 0.f};

    // ---------------- pass 1: logits -> LDS (fp16), online stats ----------------
    #pragma unroll 1
    for (int c = 0; c < 2; ++c) {
        const int m0 = wc * 128 + c * 64;
        f32x4 qk[4];
        #pragma unroll
        for (int ct = 0; ct < 4; ++ct) {
            bf16x8 b0, b1;
            if (PREP == 2) {
                const unsigned short* kr = kbf + (size_t)(b * L_ + m0 + ct * 16 + lr) * D_ + lg * 8;
                b0 = *(const bf16x8*)kr; b1 = *(const bf16x8*)(kr + 32);
            } else {
                const float* kr = K + (size_t)((b * L_ + m0 + ct * 16 + lr) * D_ + lg * 8);
                b0 = pack8n(kr); b1 = pack8n(kr + 32);
            }
            f32x4 acc = {0.f, 0.f, 0.f, 0.f};
            acc = __builtin_amdgcn_mfma_f32_16x16x32_bf16(aq[0], b0, acc, 0, 0, 0);
            acc = __builtin_amdgcn_mfma_f32_16x16x32_bf16(aq[1], b1, acc, 0, 0, 0);
            qk[ct] = acc;
        }
        const int jb = 1023 + m0 - t0 - 15;
        f32x4 pa[5];
        #pragma unroll
        for (int ss = 0; ss < 5; ++ss) {
            int j = jb + ss * 16 + lr;
            j = j < 0 ? 0 : (j > J_ - 1 ? J_ - 1 : j);
            bf16x8 b0, b1;
            if (PREP == 2) {
                const unsigned short* pr = pbf + (size_t)(b * J_ + j) * D_ + lg * 8;
                b0 = *(const bf16x8*)pr; b1 = *(const bf16x8*)(pr + 32);
            } else {
                const float* pr = P + (size_t)((b * J_ + j) * D_ + lg * 8);
                b0 = pack8n(pr); b1 = pack8n(pr + 32);
            }
            f32x4 acc = {0.f, 0.f, 0.f, 0.f};
            acc = __builtin_amdgcn_mfma_f32_16x16x32_bf16(aqp[0], b0, acc, 0, 0, 0);
            acc = __builtin_amdgcn_mfma_f32_16x16x32_bf16(aqp[1], b1, acc, 0, 0, 0);
            pa[ss] = acc;
        }
        #pragma unroll
        for (int r = 0; r < 4; ++r) {
            const int ti = lg * 4 + r;               // row within 16-tile
            const int t  = t0 + ti;
            // coalesced mask: one dword (4 cols) per lane, shfl-redistribute
            const size_t rowoff = (size_t)(b * L_ + t) * L_ + m0;
            unsigned mw;
            if (flag == 0) {
                mw = __builtin_nontemporal_load((const unsigned*)(m8 + rowoff) + lr);
            } else if (flag == 1) {
                int4 mi = ((const int4*)(m32p + rowoff))[lr];
                mw = (mi.x ? 1u : 0u) | (mi.y ? 0x100u : 0u)
                   | (mi.z ? 0x10000u : 0u) | (mi.w ? 0x1000000u : 0u);
            } else {
                float4 mv = ((const float4*)(mfp + rowoff))[lr];
                mw = (mv.x != 0.f ? 1u : 0u) | (mv.y != 0.f ? 0x100u : 0u)
                   | (mv.z != 0.f ? 0x10000u : 0u) | (mv.w != 0.f ? 0x1000000u : 0u);
            }
            const int jj = 15 + lr - ti;             // 0..30
            const int srcl = (lane & 48) | (jj & 15);
            float sv[4];
            #pragma unroll
            for (int ct = 0; ct < 4; ++ct) {
                float v0 = __shfl(pa[ct][r],     srcl);
                float v1 = __shfl(pa[ct + 1][r], srcl);
                float pos = (jj < 16) ? v0 : v1;
                float s = (qk[ct][r] + pos) * 0.125f;
                unsigned mb = ((unsigned)__shfl((int)mw, (lane & 48) | (ct * 4 + (lr >> 2)))
                               >> ((lr & 3) * 8)) & 0xFFu;
                if (mb) s = -__builtin_inff();
                sv[ct] = s;
                slogb[sidx(ti, m0 + ct * 16 + lr)] = f2h(s);
            }
            float cm = fmaxf(fmaxf(sv[0], sv[1]), fmaxf(sv[2], sv[3]));
            float mn = fmaxf(m_run[r], cm);
            float e = __expf(sv[0] - mn) + __expf(sv[1] - mn)
                    + __expf(sv[2] - mn) + __expf(sv[3] - mn);
            l_run[r] = l_run[r] * __expf(m_run[r] - mn) + e;
            m_run[r] = mn;
        }
    }
    // cross-lane merge within lr group, publish partial stats
    #pragma unroll
    for (int r = 0; r < 4; ++r) {
        float m = m_run[r], l = l_run[r];
        #pragma unroll
        for (int d = 1; d < 16; d <<= 1) {
            float mo = __shfl_xor(m, d);
            float lo = __shfl_xor(l, d);
            float mn = fmaxf(m, mo);
            l = l * __expf(m - mn) + lo * __expf(mo - mn);
            m = mn;
        }
        if (lr == 0) {
            pm[wc][lg * 4 + r][0] = m;
            pm[wc][lg * 4 + r][1] = l;
        }
    }
    __syncthreads();

    // ---------------- pass 2a: final stats + PV MFMA (no global stores) ----------
    const int rl = lr;
    float M = -1e30f;
    #pragma unroll
    for (int s2 = 0; s2 < 8; ++s2) M = fmaxf(M, pm[s2][rl][0]);
    float Ls = 0.f;
    #pragma unroll
    for (int s2 = 0; s2 < 8; ++s2) Ls += pm[s2][rl][1] * __expf(pm[s2][rl][0] - M);
    float inv = 1.0f / Ls;
    if (tid < 16) { Mrow[tid] = M; Irow[tid] = inv; }

    f32x4 acc[4] = {{0,0,0,0},{0,0,0,0},{0,0,0,0},{0,0,0,0}};
    #pragma unroll
    for (int kc = 0; kc < 4; ++kc) {
        const int colb = wc * 128 + kc * 32 + lg * 8;
        uint4v u = *(const uint4v*)&slogb[sidx(rl, colb)];
        float p0 = __expf(h2f(u[0])  - M) * inv, p1 = __expf(h2fh(u[0]) - M) * inv;
        float p2 = __expf(h2f(u[1])  - M) * inv, p3 = __expf(h2fh(u[1]) - M) * inv;
        float p4 = __expf(h2f(u[2])  - M) * inv, p5 = __expf(h2fh(u[2]) - M) * inv;
        float p6 = __expf(h2f(u[3])  - M) * inv, p7 = __expf(h2fh(u[3]) - M) * inv;
        union { bf16x8 s; uint4v u; } ap;
        ap.u[0] = cvt_pk(p0, p1); ap.u[1] = cvt_pk(p2, p3);
        ap.u[2] = cvt_pk(p4, p5); ap.u[3] = cvt_pk(p6, p7);
        #pragma unroll
        for (int ct = 0; ct < 4; ++ct) {
            bf16x8 bv;
            if (PREP >= 1) {
                bv = *(const bf16x8*)&vtg[((size_t)b * D_ + ct * 16 + lr) * L_ + colb];
            } else {
                const float* vp = V + (size_t)(b * L_ + colb) * D_ + ct * 16 + lr;
                union { bf16x8 s; uint4v u; } bb;
                bb.u[0] = cvt_pk(vp[0],   vp[64]);
                bb.u[1] = cvt_pk(vp[128], vp[192]);
                bb.u[2] = cvt_pk(vp[256], vp[320]);
                bb.u[3] = cvt_pk(vp[384], vp[448]);
                bv = bb.s;
            }
            acc[ct] = __builtin_amdgcn_mfma_f32_16x16x32_bf16(ap.s, bv, acc[ct], 0, 0, 0);
        }
    }
    __syncthreads();                                 // Mrow/Irow visible; MFMA slog reads done

    // ---------------- pass 2b: row-major coalesced NT probs stores ---------------
    #pragma unroll
    for (int half = 0; half < 2; ++half) {
        const int row = 2 * wc + half;               // wave owns 2 rows
        const float Mr = Mrow[row], Ir = Irow[row];
        float* ar = attn + (size_t)(b * L_ + t0 + row) * L_;
        #pragma unroll
        for (int it = 0; it < 4; ++it) {
            const int col0 = it * 256 + lane * 4;
            u16x4 us = *(const u16x4*)&slogb[sidx(row, col0)];
            f32x4 y;
            y[0] = __expf(h2f(us[0]) - Mr) * Ir;
            y[1] = __expf(h2f(us[1]) - Mr) * Ir;
            y[2] = __expf(h2f(us[2]) - Mr) * Ir;
            y[3] = __expf(h2f(us[3]) - Mr) * Ir;
            __builtin_nontemporal_store(y, (f32x4*)(ar + col0));   // 64 lanes = 1 KB line-aligned
        }
    }
    __syncthreads();                                 // all slog reads complete
    // partial O overlaid on slog: opart rows [wc*16, wc*16+16)
    float* opart = (float*)slogb;
    #pragma unroll
    for (int ct = 0; ct < 4; ++ct) {
        #pragma unroll
        for (int r = 0; r < 4; ++r)
            opart[oidx(wc * 16 + lg * 4 + r, ct * 16 + lr)] = acc[ct][r];
    }
    __syncthreads();
    {
        const int row = tid >> 5, dg = (tid & 31) * 2;
        f32x2 o = {0.f, 0.f};
        #pragma unroll
        for (int wq = 0; wq < 8; ++wq) {
            f32x2 z = *(f32x2*)&opart[oidx(wq * 16 + row, dg)];
            o[0] += z[0]; o[1] += z[1];
        }
        __builtin_nontemporal_store(o, (f32x2*)(out + (size_t)(b * L_ + t0 + row) * D_ + dg));
    }
}

extern "C" void kernel_launch(void* const* d_in, const int* in_sizes, int n_in,
                              void* d_out, int out_size, void* d_ws, size_t ws_size,
                              hipStream_t stream) {
    const float* q    = (const float*)d_in[0];
    const float* k    = (const float*)d_in[1];
    const float* v    = (const float*)d_in[2];
    const void*  mask = d_in[3];
    const float* P    = (const float*)d_in[4];
    const float* qp   = (const float*)d_in[5];

    float* out  = (float*)d_out;                  // [B, L, D]
    float* attn = out + B_ * L_ * D_;             // [B, L, L]

    int* flag = (int*)d_ws;
    unsigned short* vtg = (unsigned short*)((char*)d_ws + 64);
    unsigned short* kbf = vtg + (size_t)B_ * D_ * L_;
    unsigned short* pbf = kbf + (size_t)B_ * L_ * D_;
    const size_t need1 = 64 + (size_t)B_ * D_ * L_ * 2;
    const size_t need2 = need1 + (size_t)B_ * L_ * D_ * 2 + (size_t)B_ * J_ * D_ * 2;

    detect_mask_kernel<<<1, 64, 0, stream>>>((const unsigned int*)mask, flag);
    if (ws_size >= need2) {
        vtrans<<<B_ * 16, 256, 0, stream>>>(v, vtg);
        cvt_bf16_kernel<<<(B_ * L_ * D_ / 8 + 255) / 256, 256, 0, stream>>>(k, kbf, B_ * L_ * D_ / 8);
        cvt_bf16_kernel<<<(B_ * J_ * D_ / 8 + 255) / 256, 256, 0, stream>>>(P, pbf, B_ * J_ * D_ / 8);
        fused_attn<2><<<B_ * 64, 512, 0, stream>>>(q, k, qp, P, mask, flag, vtg, v, kbf, pbf, attn, out);
    } else if (ws_size >= need1) {
        vtrans<<<B_ * 16, 256, 0, stream>>>(v, vtg);
        fused_attn<1><<<B_ * 64, 512, 0, stream>>>(q, k, qp, P, mask, flag, vtg, v, kbf, pbf, attn, out);
    } else {
        fused_attn<0><<<B_ * 64, 512, 0, stream>>>(q, k, qp, P, mask, flag, vtg, v, kbf, pbf, attn, out);
    }
}